// Round 14
// baseline (99.809 us; speedup 1.0000x reference)
//
#include <hip/hip_runtime.h>
#include <hip/hip_fp16.h>

#define B 32
#define O 64
#define M 128
#define H 4
#define E 64
#define SC 2.88539008177792681f     // 2*log2(e): tanh(x) = 1 - 2/(1+exp2(SC*x))
#define LOG2E 1.44269504088896341f
#define MSTR 65                     // s_M row stride in DWORDS (130 halves): bank (lane+j)%32

#if __has_builtin(__builtin_amdgcn_exp2f)
#define EXP2F(x) __builtin_amdgcn_exp2f(x)
#else
#define EXP2F(x) __exp2f(x)
#endif

__device__ __forceinline__ float rl(float v, int lane) {
    return __uint_as_float(__builtin_amdgcn_readlane(__float_as_uint(v), lane));
}
__device__ __forceinline__ unsigned pk2h(float a, float b) {
    return (unsigned)__half_as_ushort(__float2half_rn(a)) |
           ((unsigned)__half_as_ushort(__float2half_rn(b)) << 16);
}

// ============ prep (576 blocks): 0..31 ctx -> half(exp2(SC*c)) transposed [e][m];
//   32..63 mem -> fp16 transposed [e][m]; 64..575 q_E = exp2(SC*(qW+b)) f32 ====
__global__ __launch_bounds__(256) void prep_kernel(
    const float* __restrict__ query, const float* __restrict__ context,
    const float* __restrict__ memory, const float* __restrict__ W_ch,
    const float* __restrict__ b_ch,
    __half* __restrict__ ctx_Eh, __half* __restrict__ mem_T, float* __restrict__ q_E)
{
    __shared__ float s[128 * 68];          // tile staged stride-68
    const int t = threadIdx.x, blk = blockIdx.x;

    if (blk < 64) {
        const int b = blk & 31;
        const bool is_ctx = blk < 32;
        const int e = t >> 2, mb = (t & 3) * 32;
        const float* src = (is_ctx ? context : memory) + b * (M * E);
        #pragma unroll
        for (int i = 0; i < 8; ++i) {
            int idx = i * 1024 + t * 4;
            float4 v = *(const float4*)(src + idx);
            *(float4*)(&s[(idx >> 6) * 68 + (idx & 63)]) = v;
        }
        __syncthreads();
        if (is_ctx) {
            uint4* dst = (uint4*)(ctx_Eh + (size_t)b * (E * M) + e * M + mb);
            #pragma unroll
            for (int qd = 0; qd < 4; ++qd) {
                unsigned u[4];
                #pragma unroll
                for (int k = 0; k < 4; ++k) {
                    int m0 = mb + qd * 8 + 2 * k;
                    float ea = fminf(EXP2F(SC * s[m0 * 68 + e]), 60000.f);
                    float eb = fminf(EXP2F(SC * s[(m0 + 1) * 68 + e]), 60000.f);
                    u[k] = pk2h(ea, eb);
                }
                dst[qd] = make_uint4(u[0], u[1], u[2], u[3]);
            }
        } else {
            uint4* dst = (uint4*)(mem_T + (size_t)b * (E * M) + e * M + mb);
            #pragma unroll
            for (int qd = 0; qd < 4; ++qd) {
                unsigned u[4];
                #pragma unroll
                for (int k = 0; k < 4; ++k) {
                    int m0 = mb + qd * 8 + 2 * k;
                    u[k] = pk2h(s[m0 * 68 + e], s[(m0 + 1) * 68 + e]);
                }
                dst[qd] = make_uint4(u[0], u[1], u[2], u[3]);
            }
        }
    } else {
        const int r0 = (blk - 64) * 4;      // 4 query rows (bo indices)
        s[t] = query[(r0 + (t & 3)) * 64 + (t >> 2)];
        __syncthreads();
        float bc = b_ch[t];
        float a0 = bc, a1 = bc, a2 = bc, a3 = bc;
        #pragma unroll 8
        for (int k = 0; k < 64; ++k) {
            float4 qv = *(const float4*)(&s[k * 4]);   // uniform ds_read_b128
            float wv = W_ch[k * 256 + t];
            a0 = fmaf(qv.x, wv, a0);
            a1 = fmaf(qv.y, wv, a1);
            a2 = fmaf(qv.z, wv, a2);
            a3 = fmaf(qv.w, wv, a3);
        }
        float* qa = q_E + (size_t)r0 * 256 + t;
        qa[0]   = EXP2F(SC * a0);
        qa[256] = EXP2F(SC * a1);
        qa[512] = EXP2F(SC * a2);
        qa[768] = EXP2F(SC * a3);
    }
}

// ============ main: probs never leave registers. wave = head for the whole
//   pipeline (tanh, softmax, heads); readlane broadcasts; 2 barriers total ====
__global__ __launch_bounds__(256) void attn_main(
    const __half* __restrict__ ctx_Eh, const __half* __restrict__ mem_T,
    const float* __restrict__ q_E, const float* __restrict__ w_logit,
    const float* __restrict__ b_logit, const float* __restrict__ temp,
    const float* __restrict__ W_rh, const float* __restrict__ b_rh,
    float* __restrict__ out)
{
    __shared__ __half s_E[E * M];          // [e][m] Ec fp16, 16 KB (dw-stride 64)
    __shared__ float  s_M[E * MSTR];       // [e][m-pair half2] stride 65 dw, 16.25 KB
    __shared__ float  s_po0[4 * E];        // 1 KB [wave][e'] out partials o0
    __shared__ float  s_po1[4 * E];        // 1 KB

    const int t = threadIdx.x, lane = t & 63, w = t >> 6;
    const int bo0 = blockIdx.x * 2, bo1 = bo0 + 1, b = bo0 >> 6;

    // stage ctx_Eh[b] (16 KB, b128 writes, dw-addr t -> bank t%32 free)
    {
        const uint4* g = (const uint4*)(ctx_Eh + (size_t)b * (E * M));
        uint4* l = (uint4*)s_E;
        #pragma unroll
        for (int p = 0; p < 4; ++p)
            l[p * 256 + t] = g[p * 256 + t];
    }
    // stage mem_T[b] into stride-65dw rows (row e = 64 dwords = 32 uint2)
    {
        const uint2* g = (const uint2*)(mem_T + (size_t)b * (E * M));
        const int e = t >> 2, j0 = (t & 3) * 16;       // 16 dwords per chunk
        #pragma unroll
        for (int i = 0; i < 8; ++i) {
            uint2 v = g[e * 32 + (j0 >> 1) + i];       // FIX: row stride 32 uint2
            s_M[e * MSTR + j0 + 2 * i]     = __uint_as_float(v.x);
            s_M[e * MSTR + j0 + 2 * i + 1] = __uint_as_float(v.y);
        }
    }
    const float wl  = w_logit[lane];
    const float qE0 = q_E[bo0 * 256 + t];   // Eq for (bo0, head w, e=lane)
    const float qE1 = q_E[bo1 * 256 + t];
    float sumw = wl;
    #pragma unroll
    for (int sft = 1; sft < 64; sft <<= 1) sumw += __shfl_xor(sumw, sft);
    const float bl   = b_logit[0];
    const float lsc  = LOG2E / temp[0];
    const float base = (sumw + bl) * lsc;   // logit = base + lsc2*acc
    const float lsc2 = -2.0f * lsc;
    __syncthreads();

    // tanh+logit: wave w = head, lane covers m = 2*lane, 2*lane+1, both o's.
    // q/w broadcast via readlane (VALU); single varying b32 LDS read per iter.
    float a00 = 0.f, a01 = 0.f, a10 = 0.f, a11 = 0.f;
    const __half2* Ep = (const __half2*)s_E;
    #pragma unroll 4
    for (int e = 0; e < 64; ++e) {
        float2 cf = __half22float2(Ep[e * 64 + lane]);  // varying b32, 2-way free
        float q0 = rl(qE0, e);
        float q1 = rl(qE1, e);
        float we = rl(wl, e);
        float t00 = fmaf(cf.x, q0, 1.0f);
        float t01 = fmaf(cf.y, q0, 1.0f);
        float t10 = fmaf(cf.x, q1, 1.0f);
        float t11 = fmaf(cf.y, q1, 1.0f);
        float r0 = __builtin_amdgcn_rcpf(t00 * t01);
        float r1 = __builtin_amdgcn_rcpf(t10 * t11);
        float w0 = we * r0;
        float w1 = we * r1;
        a00 = fmaf(w0, t01, a00);  a01 = fmaf(w0, t00, a01);
        a10 = fmaf(w1, t11, a10);  a11 = fmaf(w1, t10, a11);
    }

    // softmax (both o's, register-resident; probs stay UNNORMALIZED)
    float l00 = fmaf(lsc2, a00, base), l01 = fmaf(lsc2, a01, base);
    float l10 = fmaf(lsc2, a10, base), l11 = fmaf(lsc2, a11, base);
    float mx0 = fmaxf(l00, l01), mx1 = fmaxf(l10, l11);
    #pragma unroll
    for (int sft = 1; sft < 64; sft <<= 1) {
        mx0 = fmaxf(mx0, __shfl_xor(mx0, sft));
        mx1 = fmaxf(mx1, __shfl_xor(mx1, sft));
    }
    float e00 = EXP2F(l00 - mx0), e01 = EXP2F(l01 - mx0);
    float e10 = EXP2F(l10 - mx1), e11 = EXP2F(l11 - mx1);
    float s0 = e00 + e01, s1 = e10 + e11;
    #pragma unroll
    for (int sft = 1; sft < 64; sft <<= 1) {
        s0 += __shfl_xor(s0, sft);
        s1 += __shfl_xor(s1, sft);
    }
    float rs0 = __builtin_amdgcn_rcpf(s0), rs1 = __builtin_amdgcn_rcpf(s1);

    // heads: wave w computes ITS OWN head over all m; probs broadcast via
    // readlane from this wave's registers; mem column-pair via varying b32.
    float h0 = 0.f, h1 = 0.f;
    {
        const float* mrow = &s_M[lane * MSTR];
        #pragma unroll 8
        for (int j = 0; j < 64; ++j) {
            __half2 mh = *(const __half2*)&mrow[j];     // (mem[2j][e], mem[2j+1][e])
            float2 mv = __half22float2(mh);
            float p00 = rl(e00, j), p01 = rl(e01, j);   // o0 probs m=2j,2j+1
            float p10 = rl(e10, j), p11 = rl(e11, j);
            h0 = fmaf(p00, mv.x, h0); h0 = fmaf(p01, mv.y, h0);
            h1 = fmaf(p10, mv.x, h1); h1 = fmaf(p11, mv.y, h1);
        }
    }
    float hv0 = h0 * rs0;
    float hv1 = h1 * rs1;
    hv0 = (hv0 > 0.f) ? hv0 : 0.01f * hv0;   // leaky relu; heads[h=w][e=lane]
    hv1 = (hv1 > 0.f) ? hv1 : 0.01f * hv1;

    // fused output projection: wave w owns rows j = w*64..w*64+63 of W_rh
    {
        float acc0 = 0.f, acc1 = 0.f;
        const float* Wp = W_rh + (w * 64) * 64 + lane;
        #pragma unroll 8
        for (int jj = 0; jj < 64; ++jj) {
            float wv = Wp[jj * 64];
            acc0 = fmaf(rl(hv0, jj), wv, acc0);
            acc1 = fmaf(rl(hv1, jj), wv, acc1);
        }
        s_po0[w * 64 + lane] = acc0;
        s_po1[w * 64 + lane] = acc1;
    }
    __syncthreads();
    if (t < 64) {
        float o = s_po0[t] + s_po0[64 + t] + s_po0[128 + t] + s_po0[192 + t] + b_rh[t];
        out[(size_t)bo0 * 64 + t] = o;
    } else if (t < 128) {
        int e2 = t - 64;
        float o = s_po1[e2] + s_po1[64 + e2] + s_po1[128 + e2] + s_po1[192 + e2] + b_rh[e2];
        out[(size_t)bo1 * 64 + e2] = o;
    }
}

extern "C" void kernel_launch(void* const* d_in, const int* in_sizes, int n_in,
                              void* d_out, int out_size, void* d_ws, size_t ws_size,
                              hipStream_t stream) {
    const float* query   = (const float*)d_in[0];
    const float* context = (const float*)d_in[1];
    const float* memory  = (const float*)d_in[2];
    const float* W_ch    = (const float*)d_in[3];
    const float* b_ch    = (const float*)d_in[4];
    const float* w_logit = (const float*)d_in[5];
    const float* b_logit = (const float*)d_in[6];
    const float* W_rh    = (const float*)d_in[7];
    const float* b_rh    = (const float*)d_in[8];
    const float* temp    = (const float*)d_in[9];
    float* out = (float*)d_out;

    // workspace carve: ctx_Eh 512K | mem_T 512K | q_E 2M
    __half* ctx_Eh  = (__half*)d_ws;
    __half* mem_T   = ctx_Eh + (size_t)B * E * M;
    float*  q_E     = (float*)(mem_T + (size_t)B * E * M);

    prep_kernel<<<576, 256, 0, stream>>>(query, context, memory, W_ch, b_ch,
                                         ctx_Eh, mem_T, q_E);
    attn_main<<<B * O / 2, 256, 0, stream>>>(ctx_Eh, mem_T, q_E, w_logit,
                                             b_logit, temp, W_rh, b_rh, out);
}